// Round 4
// baseline (1078.227 us; speedup 1.0000x reference)
//
#include <hip/hip_runtime.h>
#include <hip/hip_bf16.h>

#define HH 256
#define SSL 512
#define G3 768

using short8 = __attribute__((ext_vector_type(8))) short;
using f32x4  = __attribute__((ext_vector_type(4))) float;

__device__ __forceinline__ unsigned short f2bf(float f) {
  unsigned int u = __float_as_uint(f);
  u += 0x7FFFu + ((u >> 16) & 1u);
  return (unsigned short)(u >> 16);
}
__device__ __forceinline__ float bf2f(unsigned short b) {
  return __uint_as_float(((unsigned int)b) << 16);
}
// m201-pattern end-of-step sync: targeted lgkm drain, raw barrier, sched pin.
// No vmcnt drain -> global prefetch stays in flight across the barrier.
__device__ __forceinline__ void sync_step() {
  asm volatile("s_waitcnt lgkmcnt(0)" ::: "memory");
  __builtin_amdgcn_s_barrier();
  __builtin_amdgcn_sched_barrier(0);
}

// ---------------------------------------------------------------------------
// Prep: pack W_ih -> bf16 [j][k] rows; W_hh -> bf16 MFMA-fragment image.
// F(w,g,mt,kt) = ((w*3+g)*4+mt)*8+kt, w=wave, g gate, mt 16-row tile, kt K=32.
// row = g*256 + w*64 + mt*16 + (l&15); k0 = kt*32 + (l>>4)*8.
// ---------------------------------------------------------------------------
__global__ __launch_bounds__(256) void prep_pack(
    const float* __restrict__ Wih, const float* __restrict__ Whh,
    unsigned short* __restrict__ wih_bf, unsigned short* __restrict__ whh_frag)
{
  int blk = blockIdx.x;
  if (blk < 96) {
    int base = (blk * 256 + threadIdx.x) * 4;
#pragma unroll
    for (int i = 0; i < 4; i++) {
      int u = base + i;                      // 0..98303 u32-pairs
      float a = Wih[2 * u], b = Wih[2 * u + 1];
      ((unsigned int*)wih_bf)[u] = (unsigned int)f2bf(a) | ((unsigned int)f2bf(b) << 16);
    }
  } else {
    int gid = (blk - 96) * 256 + threadIdx.x;  // 0..24575
    int f = gid >> 6, l = gid & 63;
    int kt = f & 7, mt = (f >> 3) & 3, g = (f >> 5) % 3, w = f / 96;
    int row = g * HH + w * 64 + mt * 16 + (l & 15);
    int k0  = kt * 32 + (l >> 4) * 8;
    const float* src = Whh + (size_t)row * HH + k0;
    unsigned int o[4];
#pragma unroll
    for (int i = 0; i < 4; i++)
      o[i] = (unsigned int)f2bf(src[2 * i]) | ((unsigned int)f2bf(src[2 * i + 1]) << 16);
    *(uint4*)(whh_frag + ((size_t)f * 64 + l) * 8) = *(uint4*)o;
  }
}

// ---------------------------------------------------------------------------
// Kernel 1 (R9): full-K staged once; loop 6 j-tiles. NEW: T14 async W-stage
// (issue next-jb W loads BEFORE the MFMA loop, LDS-write after epilogue) and
// barrier count cut 7->5 per jb. R8 post-mortem: 1 block/CU exposes every
// serial phase; this hides the W L2-latency+BW under MFMA+epilogue.
// ---------------------------------------------------------------------------
__global__ __launch_bounds__(512, 2) void gi_gemm(
    const float* __restrict__ X, const unsigned short* __restrict__ Wb,
    const float* __restrict__ bih, const float* __restrict__ bhh,
    unsigned short* __restrict__ gi)
{
  __shared__ __align__(16) unsigned short Al[128 * 256];  // [s][256h], swizzled per 64-slice
  __shared__ __align__(16) unsigned short Bl[128 * 256];  // [j][256k], swizzled per 64-slice
  __shared__ __align__(16) unsigned short Dl[64][136];    // bf16 epilogue staging
  __shared__ float biasl[G3];

  const int tid  = threadIdx.x;
  const int lane = tid & 63;
  const int wave = tid >> 6;
  const int wm   = wave >> 2;   // 0..1: M half (64 s-rows)
  const int wn   = wave & 3;    // 0..3: N quarter (32 j-cols)
  const int n16  = lane & 15;
  const int quad = lane >> 4;

  const int mblk = blockIdx.x;
  const int b    = mblk >> 2;
  const int s0   = (mblk & 3) * 128;

  const float* Xb = X + (size_t)b * (HH * SSL);

  // bias to LDS: bias[j] = bih[j] + (j<512 ? bhh[j] : 0)
  for (int i = tid; i < G3; i += 512)
    biasl[i] = bih[i] + (i < 2 * HH ? bhh[i] : 0.f);

  // ---- stage A: all 4 kt slices, transpose+convert, swizzled ----
  float4 xs[4][2][2];
#pragma unroll
  for (int kt = 0; kt < 4; kt++)
#pragma unroll
    for (int q = 0; q < 2; q++) {
      int idx = tid + 512 * q, sq = idx & 31, a = idx >> 5;
      const float* p = Xb + (size_t)(kt * 64 + 2 * a) * SSL + s0 + 4 * sq;
      xs[kt][q][0] = *(const float4*)p;
      xs[kt][q][1] = *(const float4*)(p + SSL);
    }
#pragma unroll
  for (int kt = 0; kt < 4; kt++)
#pragma unroll
    for (int q = 0; q < 2; q++) {
      int idx = tid + 512 * q, sq = idx & 31, a = idx >> 5;
      int c = a >> 2, d = a & 3;
#pragma unroll
      for (int r = 0; r < 4; r++) {
        int s = 4 * sq + r;
        int sw = (s + (s >> 3)) & 7;
        unsigned int u =
            (unsigned int)f2bf(((const float*)&xs[kt][q][0])[r]) |
            ((unsigned int)f2bf(((const float*)&xs[kt][q][1])[r]) << 16);
        *(unsigned int*)(Al + s * 256 + kt * 64 + ((c ^ sw) * 8) + d * 2) = u;
      }
    }

  // ---- stage B for jb=0 ----
  {
    uint4 wv0[8];
#pragma unroll
    for (int p = 0; p < 8; p++) {
      int cid = tid + 512 * p, j = cid >> 5, c = cid & 31;
      wv0[p] = *(const uint4*)(Wb + (size_t)(0 * 128 + j) * HH + c * 8);
    }
#pragma unroll
    for (int p = 0; p < 8; p++) {
      int cid = tid + 512 * p, j = cid >> 5, c = cid & 31;
      int sw = (j + (j >> 3)) & 7;
      *(uint4*)(Bl + j * 256 + (c >> 3) * 64 + (((c & 7) ^ sw) * 8)) = wv0[p];
    }
  }
  __syncthreads();

  // ---- hoist A fragments: af[mt][kkk], reused for all 6 j-tiles ----
  short8 af[4][8];
#pragma unroll
  for (int mt = 0; mt < 4; mt++) {
    int s = wm * 64 + mt * 16 + n16;
    int sw = (s + (s >> 3)) & 7;
#pragma unroll
    for (int kkk = 0; kkk < 8; kkk++) {
      int kt = kkk >> 1, c3 = (kkk & 1) * 4 + quad;
      af[mt][kkk] = *(const short8*)(Al + s * 256 + kt * 64 + ((c3 ^ sw) * 8));
    }
  }

  for (int jb = 0; jb < 6; jb++) {
    float bb0 = biasl[jb * 128 + wn * 32 + 0 * 16 + n16];
    float bb1 = biasl[jb * 128 + wn * 32 + 1 * 16 + n16];

    // T14: issue next-jb W loads NOW; latency+BW hide under MFMA+epilogue
    uint4 wv[8];
    if (jb < 5) {
#pragma unroll
      for (int p = 0; p < 8; p++) {
        int cid = tid + 512 * p, j = cid >> 5, c = cid & 31;
        wv[p] = *(const uint4*)(Wb + (size_t)((jb + 1) * 128 + j) * HH + c * 8);
      }
    }

    f32x4 acc[4][2];
#pragma unroll
    for (int mt = 0; mt < 4; mt++)
#pragma unroll
      for (int nt = 0; nt < 2; nt++) acc[mt][nt] = f32x4{0.f, 0.f, 0.f, 0.f};

#pragma unroll
    for (int kkk = 0; kkk < 8; kkk++) {
      short8 bfr[2];
      int kt = kkk >> 1, c3 = (kkk & 1) * 4 + quad;
#pragma unroll
      for (int nt = 0; nt < 2; nt++) {
        int j = wn * 32 + nt * 16 + n16;
        int sw = (j + (j >> 3)) & 7;
        bfr[nt] = *(const short8*)(Bl + j * 256 + kt * 64 + ((c3 ^ sw) * 8));
      }
#pragma unroll
      for (int mt = 0; mt < 4; mt++)
#pragma unroll
        for (int nt = 0; nt < 2; nt++)
          acc[mt][nt] = __builtin_amdgcn_mfma_f32_16x16x32_bf16(af[mt][kkk], bfr[nt], acc[mt][nt], 0, 0, 0);
    }
    __syncthreads();   // sync0: Bl MFMA-reads + prev Dl reads done

    // ---- epilogue: two 64-row halves through bf16 LDS, coalesced stores ----
    if (wm == 0) {
#pragma unroll
      for (int mt = 0; mt < 4; mt++)
#pragma unroll
        for (int nt = 0; nt < 2; nt++) {
          float bb = nt ? bb1 : bb0;
#pragma unroll
          for (int r = 0; r < 4; r++)
            Dl[mt * 16 + quad * 4 + r][wn * 32 + nt * 16 + n16] =
                f2bf(acc[mt][nt][r] + bb);
        }
    }
    __syncthreads();   // sync1
    {
      int row = tid >> 3, seg = tid & 7;
      short8 v0 = *(const short8*)&Dl[row][seg * 16];
      short8 v1 = *(const short8*)&Dl[row][seg * 16 + 8];
      size_t go = ((size_t)(b * SSL + s0 + row)) * G3 + jb * 128 + seg * 16;
      *(short8*)(gi + go) = v0;
      *(short8*)(gi + go + 8) = v1;
    }
    __syncthreads();   // sync2: half-0 reads done before half-1 writes
    if (wm == 1) {
#pragma unroll
      for (int mt = 0; mt < 4; mt++)
#pragma unroll
        for (int nt = 0; nt < 2; nt++) {
          float bb = nt ? bb1 : bb0;
#pragma unroll
          for (int r = 0; r < 4; r++)
            Dl[mt * 16 + quad * 4 + r][wn * 32 + nt * 16 + n16] =
                f2bf(acc[mt][nt][r] + bb);
        }
    }
    __syncthreads();   // sync3
    {
      int row = tid >> 3, seg = tid & 7;
      short8 v0 = *(const short8*)&Dl[row][seg * 16];
      short8 v1 = *(const short8*)&Dl[row][seg * 16 + 8];
      size_t go = ((size_t)(b * SSL + s0 + 64 + row)) * G3 + jb * 128 + seg * 16;
      *(short8*)(gi + go) = v0;
      *(short8*)(gi + go + 8) = v1;
    }

    // ---- write prefetched W into Bl (loads have had ~2us to land) ----
    if (jb < 5) {
#pragma unroll
      for (int p = 0; p < 8; p++) {
        int cid = tid + 512 * p, j = cid >> 5, c = cid & 31;
        int sw = (j + (j >> 3)) & 7;
        *(uint4*)(Bl + j * 256 + (c >> 3) * 64 + (((c & 7) ^ sw) * 8)) = wv[p];
      }
      __syncthreads();   // sync4: Bl ready; also orders Dl half-1 reads vs next jb
    }
  }
}

// ---------------------------------------------------------------------------
// Kernel 2: persistent GRU scan. 64 blocks x 4 rows, 256 thr, 1 wave/SIMD.
// R9: test MFMA dep-latency hypothesis. R8 accounting left ~1700cy/step
// unexplained; 6 chains x 16-deep at 30cy spacing stalls if MFMA->MFMA
// same-acc latency L > 30. Restructure: merge mp passes -> 12 independent
// chains x 8 deep (accr/accz/accn[4]); region = max(480, 8L) vs 16L.
// To fit VGPRs: 8 n-gate frags (mt 0..3, kt 6..7) move to LDS (32KB),
// ds_read-issued 2 kt early (latency hidden under 24 MFMAs).
// ---------------------------------------------------------------------------
__global__ __launch_bounds__(256, 1) void gru_scan(
    const float* __restrict__ tree, const int* __restrict__ mask,
    const unsigned short* __restrict__ wfrag, const float* __restrict__ bhh,
    const unsigned short* __restrict__ gi, float* __restrict__ out)
{
  __shared__ __align__(16) unsigned short wlds[32 * 512];  // 32 frags x 1KB
  // slot(kt,b,q) = kt*17 + b*4 + q (16B units); 17-pad spreads banks
  __shared__ __align__(16) unsigned short hbuf[2][1088];
  __shared__ int lsum[4];

  const int tid  = threadIdx.x;
  const int lane = tid & 63;
  const int w    = tid >> 6;
  const int n16  = lane & 15;
  const int quad = lane >> 4;
  const int b    = n16 & 3;          // batch row owned by this lane
  const int rep  = n16 >> 2;         // replica index -> owns mt tile = rep
  const int brow0 = blockIdx.x * 4;
  const int jbase = w * 64 + rep * 16 + quad * 4;  // 4 owned j's

  if (tid < 4) lsum[tid] = 0;

  // stage LDS frags: n-gate, kt 6..7, all waves' mt tiles (32 frags)
#pragma unroll
  for (int i = 0; i < 8; i++) {
    int cid = tid + 256 * i;         // 0..2047
    int l = cid & 63, f = cid >> 6;  // f = ((wp*4+mt)*2+k)
    int wp = f >> 3, mt = (f >> 1) & 3, k = f & 1;
    int F = ((wp * 3 + 2) * 4 + mt) * 8 + 6 + k;
    *(uint4*)(wlds + ((size_t)f * 64 + l) * 8) =
        *(const uint4*)(wfrag + ((size_t)F * 64 + l) * 8);
  }

  // initial h (lane-resident, f32)
  f32x4 h4 = *(const f32x4*)(tree + (size_t)(brow0 + b) * HH + jbase);

  const int wslot = ((w * 2 + (rep >> 1)) * 17 + b * 4 + ((rep & 1) * 2 + (quad >> 1))) * 8
                  + (quad & 1) * 4;
  {
    unsigned long long u =
        (unsigned long long)((unsigned)f2bf(h4[0]) | ((unsigned)f2bf(h4[1]) << 16)) |
        ((unsigned long long)((unsigned)f2bf(h4[2]) | ((unsigned)f2bf(h4[3]) << 16)) << 32);
    *(unsigned long long*)&hbuf[0][wslot] = u;
  }
  {
    const int* mp = mask + (size_t)(brow0 + w) * SSL + lane * 8;
    int4 a = *(const int4*)mp;
    int4 c = *(const int4*)(mp + 4);
    atomicAdd(&lsum[w], a.x + a.y + a.z + a.w + c.x + c.y + c.z + c.w);
  }

  // W fragments: r,z gates -> AGPR (64 frags = 256 AGPR);
  // n gate kt 0..5 -> VGPR (24 frags = 96 VGPR); kt 6..7 from LDS per step.
  short8 awA[2][4][8];
  short8 awV[4][6];
#pragma unroll
  for (int g = 0; g < 2; g++)
#pragma unroll
    for (int mt = 0; mt < 4; mt++)
#pragma unroll
      for (int kt = 0; kt < 8; kt++) {
        int F = ((w * 3 + g) * 4 + mt) * 8 + kt;
        awA[g][mt][kt] = *(const short8*)(wfrag + ((size_t)F * 64 + lane) * 8);
      }
#pragma unroll
  for (int mt = 0; mt < 4; mt++)
#pragma unroll
    for (int kt = 0; kt < 6; kt++) {
      int F = ((w * 3 + 2) * 4 + mt) * 8 + kt;
      awV[mt][kt] = *(const short8*)(wfrag + ((size_t)F * 64 + lane) * 8);
    }
  // Pin: opaque to remat; forces register class (R5 lesson).
#pragma unroll
  for (int g = 0; g < 2; g++)
#pragma unroll
    for (int mt = 0; mt < 4; mt++)
#pragma unroll
      for (int kt = 0; kt < 8; kt++)
        asm volatile("" : "+a"(awA[g][mt][kt]));
#pragma unroll
  for (int mt = 0; mt < 4; mt++)
#pragma unroll
    for (int kt = 0; kt < 6; kt++)
      asm volatile("" : "+v"(awV[mt][kt]));

  f32x4 bh4 = *(const f32x4*)(bhh + 2 * HH + jbase);

  // per-lane gi stream: batch row b, j's = jbase..jbase+3, 3 gates (8B each)
  const unsigned short* gip = gi + (size_t)(brow0 + b) * SSL * G3 + jbase;
  unsigned long long gA[3], gB[3];
#pragma unroll
  for (int g = 0; g < 3; g++) gA[g] = *(const unsigned long long*)(gip + (size_t)0 * G3 + g * HH);
#pragma unroll
  for (int g = 0; g < 3; g++) gB[g] = *(const unsigned long long*)(gip + (size_t)1 * G3 + g * HH);

  __syncthreads();
  int mylast = lsum[b] - 1; if (mylast < 0) mylast = 0;

  auto step = [&](int t, unsigned long long* gv) {
    const int cb = t & 1, nb = cb ^ 1;
    unsigned long long g0 = gv[0], g1 = gv[1], g2 = gv[2];

    // hb fragments first (starts LDS latency early)
    const unsigned short* hp = &hbuf[cb][0] + ((n16 & 3) * 4 + quad) * 8;
    short8 hb[8];
#pragma unroll
    for (int kt = 0; kt < 8; kt++)
      hb[kt] = *(const short8*)(hp + kt * (17 * 8));

    // prefetch gi for t+2 (covered by ~1 full step; no vmcnt drain at barrier)
    int tn = (t + 2 < SSL) ? t + 2 : SSL - 1;
    gv[0] = *(const unsigned long long*)(gip + (size_t)tn * G3 + 0 * HH);
    gv[1] = *(const unsigned long long*)(gip + (size_t)tn * G3 + 1 * HH);
    gv[2] = *(const unsigned long long*)(gip + (size_t)tn * G3 + 2 * HH);

    // ---- MFMA: 12 independent chains x 8 deep ----
    f32x4 accr[4], accz[4], accn[4];
#pragma unroll
    for (int m = 0; m < 4; m++) {
      accr[m] = f32x4{0.f, 0.f, 0.f, 0.f};
      accz[m] = f32x4{0.f, 0.f, 0.f, 0.f};
      accn[m] = f32x4{0.f, 0.f, 0.f, 0.f};
    }
    short8 w2a[4], w2b[4];
#pragma unroll
    for (int kt = 0; kt < 8; kt++) {
      if (kt == 4) {
#pragma unroll
        for (int m = 0; m < 4; m++)
          w2a[m] = *(const short8*)(wlds + ((size_t)(((w * 4 + m) * 2 + 0)) * 64 + lane) * 8);
      }
      if (kt == 6) {
#pragma unroll
        for (int m = 0; m < 4; m++)
          w2b[m] = *(const short8*)(wlds + ((size_t)(((w * 4 + m) * 2 + 1)) * 64 + lane) * 8);
      }
#pragma unroll
      for (int m = 0; m < 4; m++)
        accr[m] = __builtin_amdgcn_mfma_f32_16x16x32_bf16(awA[0][m][kt], hb[kt], accr[m], 0, 0, 0);
#pragma unroll
      for (int m = 0; m < 4; m++)
        accz[m] = __builtin_amdgcn_mfma_f32_16x16x32_bf16(awA[1][m][kt], hb[kt], accz[m], 0, 0, 0);
#pragma unroll
      for (int m = 0; m < 4; m++) {
        short8 wn = (kt < 6) ? awV[m][kt] : ((kt == 6) ? w2a[m] : w2b[m]);
        accn[m] = __builtin_amdgcn_mfma_f32_16x16x32_bf16(wn, hb[kt], accn[m], 0, 0, 0);
      }
    }

    // lane picks its own mt tile = rep
    f32x4 selR = (rep == 0) ? accr[0] : (rep == 1) ? accr[1] : (rep == 2) ? accr[2] : accr[3];
    f32x4 selZ = (rep == 0) ? accz[0] : (rep == 1) ? accz[1] : (rep == 2) ? accz[2] : accz[3];
    f32x4 selN = (rep == 0) ? accn[0] : (rep == 1) ? accn[1] : (rep == 2) ? accn[2] : accn[3];

    // ---- gates in-register: 4 (j,b) elements per lane ----
#pragma unroll
    for (int e = 0; e < 4; e++) {
      float gr = bf2f((unsigned short)((g0 >> (16 * e)) & 0xFFFFull));
      float gz = bf2f((unsigned short)((g1 >> (16 * e)) & 0xFFFFull));
      float gn = bf2f((unsigned short)((g2 >> (16 * e)) & 0xFFFFull));
      float r = __builtin_amdgcn_rcpf(1.f + __expf(-(selR[e] + gr)));
      float z = __builtin_amdgcn_rcpf(1.f + __expf(-(selZ[e] + gz)));
      float a = gn + r * (selN[e] + bh4[e]);
      float nn = 1.f - 2.f * __builtin_amdgcn_rcpf(__expf(2.f * a) + 1.f);
      h4[e] = nn + z * (h4[e] - nn);
    }
    {
      unsigned long long u =
          (unsigned long long)((unsigned)f2bf(h4[0]) | ((unsigned)f2bf(h4[1]) << 16)) |
          ((unsigned long long)((unsigned)f2bf(h4[2]) | ((unsigned)f2bf(h4[3]) << 16)) << 32);
      *(unsigned long long*)&hbuf[nb][wslot] = u;
    }
    if (t == mylast) {   // per-lane predicate (last unmasked timestep of batch b)
      *(f32x4*)(out + (size_t)(brow0 + b) * HH + jbase) = h4;
    }
    sync_step();
  };

  for (int t = 0; t < SSL; t += 2) {
    step(t, gA);
    step(t + 1, gB);
  }
}

extern "C" void kernel_launch(void* const* d_in, const int* in_sizes, int n_in,
                              void* d_out, int out_size, void* d_ws, size_t ws_size,
                              hipStream_t stream) {
  const float* tree = (const float*)d_in[0];
  const float* seq  = (const float*)d_in[1];
  const int*   mask = (const int*)d_in[2];
  const float* Wih  = (const float*)d_in[3];
  const float* Whh  = (const float*)d_in[4];
  const float* bih  = (const float*)d_in[5];
  const float* bhh  = (const float*)d_in[6];
  float* out = (float*)d_out;

  unsigned short* gi      = (unsigned short*)d_ws;                       // 201,326,592 B
  unsigned short* wih_bf  = (unsigned short*)((char*)d_ws + 201326592);  // 393,216 B
  unsigned short* whh_frag= (unsigned short*)((char*)d_ws + 201719808);  // 393,216 B

  prep_pack<<<192, 256, 0, stream>>>(Wih, Whh, wih_bf, whh_frag);
  gi_gemm<<<1024, 512, 0, stream>>>(seq, wih_bf, bih, bhh, gi);
  gru_scan<<<64, 256, 0, stream>>>(tree, mask, whh_frag, bhh, gi, out);
}

// Round 6
// 861.288 us; speedup vs baseline: 1.2519x; 1.2519x over previous
//
#include <hip/hip_runtime.h>
#include <hip/hip_bf16.h>

#define HH 256
#define SSL 512
#define G3 768

#define AS1 __attribute__((address_space(1)))
#define AS3 __attribute__((address_space(3)))

using short8 = __attribute__((ext_vector_type(8))) short;
using f32x4  = __attribute__((ext_vector_type(4))) float;

__device__ __forceinline__ unsigned short f2bf(float f) {
  unsigned int u = __float_as_uint(f);
  u += 0x7FFFu + ((u >> 16) & 1u);
  return (unsigned short)(u >> 16);
}
__device__ __forceinline__ float bf2f(unsigned short b) {
  return __uint_as_float(((unsigned int)b) << 16);
}
// m201-pattern end-of-step sync: targeted lgkm drain, raw barrier, sched pin.
// No vmcnt drain -> global prefetch stays in flight across the barrier.
__device__ __forceinline__ void sync_step() {
  asm volatile("s_waitcnt lgkmcnt(0)" ::: "memory");
  __builtin_amdgcn_s_barrier();
  __builtin_amdgcn_sched_barrier(0);
}

// ---------------------------------------------------------------------------
// Prep (R10): W_ih -> PRE-SWIZZLED Bl LDS image (16B chunks in the exact
// layout gi_gemm's global_load_lds writes linearly), per 128-j tile.
// chunk(jb,j,c) -> wih_bf[jb*4096 + j*32 + (c>>3)*8 + ((c&7)^sw)], sw=(j+(j>>3))&7
// holds bf16 of Wih[jb*128+j][c*8..c*8+7].
// W_hh -> MFMA-fragment image: F(w,g,mt,kt) = ((w*3+g)*4+mt)*8+kt (unchanged).
// ---------------------------------------------------------------------------
__global__ __launch_bounds__(256) void prep_pack(
    const float* __restrict__ Wih, const float* __restrict__ Whh,
    unsigned short* __restrict__ wih_bf, unsigned short* __restrict__ whh_frag)
{
  int blk = blockIdx.x;
  if (blk < 96) {
    int chunk = blk * 256 + threadIdx.x;   // 0..24575
    int jb = chunk >> 12;                  // 0..5
    int rem = chunk & 4095;
    int j = rem >> 5;                      // 0..127
    int c = rem & 31;                      // 0..31
    const float* src = Wih + (size_t)(jb * 128 + j) * HH + c * 8;
    unsigned int o[4];
#pragma unroll
    for (int i = 0; i < 4; i++)
      o[i] = (unsigned int)f2bf(src[2 * i]) | ((unsigned int)f2bf(src[2 * i + 1]) << 16);
    int sw = (j + (j >> 3)) & 7;
    size_t dst = (size_t)jb * 4096 + j * 32 + (c >> 3) * 8 + ((c & 7) ^ sw);
    *(uint4*)(wih_bf + dst * 8) = *(uint4*)o;
  } else {
    int gid = (blk - 96) * 256 + threadIdx.x;  // 0..24575
    int f = gid >> 6, l = gid & 63;
    int kt = f & 7, mt = (f >> 3) & 3, g = (f >> 5) % 3, w = f / 96;
    int row = g * HH + w * 64 + mt * 16 + (l & 15);
    int k0  = kt * 32 + (l >> 4) * 8;
    const float* src = Whh + (size_t)row * HH + k0;
    unsigned int o[4];
#pragma unroll
    for (int i = 0; i < 4; i++)
      o[i] = (unsigned int)f2bf(src[2 * i]) | ((unsigned int)f2bf(src[2 * i + 1]) << 16);
    *(uint4*)(whh_frag + ((size_t)f * 64 + l) * 8) = *(uint4*)o;
  }
}

// ---------------------------------------------------------------------------
// Kernel 1 (R10): full-K A staged once; loop 6 j-tiles. B-staging via
// global_load_lds(16B) from the pre-swizzled W image (no VGPR round-trip,
// no ds_writes); epilogue stores bf16 DIRECTLY to gi (no Dl LDS pass).
// Barriers per jb: 5 -> 2. LDS: A 64K + B 64K + bias 3K = 131K -> 1 blk/CU.
// ---------------------------------------------------------------------------
__global__ __launch_bounds__(512, 2) void gi_gemm(
    const float* __restrict__ X, const unsigned short* __restrict__ Wb,
    const float* __restrict__ bih, const float* __restrict__ bhh,
    unsigned short* __restrict__ gi)
{
  __shared__ __align__(16) unsigned short Al[128 * 256];  // [s][256h], swizzled per 64-slice
  __shared__ __align__(16) unsigned short Bl[128 * 256];  // [j][256k], swizzled per 64-slice
  __shared__ float biasl[G3];

  const int tid  = threadIdx.x;
  const int lane = tid & 63;
  const int wave = tid >> 6;
  const int wm   = wave >> 2;   // 0..1: M half (64 s-rows)
  const int wn   = wave & 3;    // 0..3: N quarter (32 j-cols)
  const int n16  = lane & 15;
  const int quad = lane >> 4;

  const int mblk = blockIdx.x;
  const int b    = mblk >> 2;
  const int s0   = (mblk & 3) * 128;

  const float* Xb = X + (size_t)b * (HH * SSL);

  // bias to LDS: bias[j] = bih[j] + (j<512 ? bhh[j] : 0)
  for (int i = tid; i < G3; i += 512)
    biasl[i] = bih[i] + (i < 2 * HH ? bhh[i] : 0.f);

  // ---- stage A: issue all 16 float4 loads (oldest), then jb0 B gl_lds ----
  float4 xs[4][2][2];
#pragma unroll
  for (int kt = 0; kt < 4; kt++)
#pragma unroll
    for (int q = 0; q < 2; q++) {
      int idx = tid + 512 * q, sq = idx & 31, a = idx >> 5;
      const float* p = Xb + (size_t)(kt * 64 + 2 * a) * SSL + s0 + 4 * sq;
      xs[kt][q][0] = *(const float4*)p;
      xs[kt][q][1] = *(const float4*)(p + SSL);
    }
  // jb=0 B-stage: 64 wave-issues x 1KB, linear LDS dest, pre-swizzled source
#pragma unroll
  for (int i = 0; i < 8; i++) {
    int cid = wave * 8 + i;   // 0..63
    const unsigned short* src = Wb + ((size_t)(0 * 4096 + cid * 64 + lane)) * 8;
    __builtin_amdgcn_global_load_lds((const AS1 unsigned int*)src,
                                     (AS3 unsigned int*)(Bl + (size_t)cid * 512),
                                     16, 0, 0);
  }
  // A transpose+convert (compiler waits xs loads; gl_lds stays outstanding)
#pragma unroll
  for (int kt = 0; kt < 4; kt++)
#pragma unroll
    for (int q = 0; q < 2; q++) {
      int idx = tid + 512 * q, sq = idx & 31, a = idx >> 5;
      int c = a >> 2, d = a & 3;
#pragma unroll
      for (int r = 0; r < 4; r++) {
        int s = 4 * sq + r;
        int sw = (s + (s >> 3)) & 7;
        unsigned int u =
            (unsigned int)f2bf(((const float*)&xs[kt][q][0])[r]) |
            ((unsigned int)f2bf(((const float*)&xs[kt][q][1])[r]) << 16);
        *(unsigned int*)(Al + s * 256 + kt * 64 + ((c ^ sw) * 8) + d * 2) = u;
      }
    }
  __syncthreads();   // drains lgkm + vmcnt(0): Al written, Bl(jb0) landed

  // ---- hoist A fragments: af[mt][kkk], reused for all 6 j-tiles ----
  short8 af[4][8];
#pragma unroll
  for (int mt = 0; mt < 4; mt++) {
    int s = wm * 64 + mt * 16 + n16;
    int sw = (s + (s >> 3)) & 7;
#pragma unroll
    for (int kkk = 0; kkk < 8; kkk++) {
      int kt = kkk >> 1, c3 = (kkk & 1) * 4 + quad;
      af[mt][kkk] = *(const short8*)(Al + s * 256 + kt * 64 + ((c3 ^ sw) * 8));
    }
  }

  for (int jb = 0; jb < 6; jb++) {
    float bb0 = biasl[jb * 128 + wn * 32 + 0 * 16 + n16];
    float bb1 = biasl[jb * 128 + wn * 32 + 1 * 16 + n16];

    f32x4 acc[4][2];
#pragma unroll
    for (int mt = 0; mt < 4; mt++)
#pragma unroll
      for (int nt = 0; nt < 2; nt++) acc[mt][nt] = f32x4{0.f, 0.f, 0.f, 0.f};

#pragma unroll
    for (int kkk = 0; kkk < 8; kkk++) {
      short8 bfr[2];
      int kt = kkk >> 1, c3 = (kkk & 1) * 4 + quad;
#pragma unroll
      for (int nt = 0; nt < 2; nt++) {
        int j = wn * 32 + nt * 16 + n16;
        int sw = (j + (j >> 3)) & 7;
        bfr[nt] = *(const short8*)(Bl + j * 256 + kt * 64 + ((c3 ^ sw) * 8));
      }
#pragma unroll
      for (int mt = 0; mt < 4; mt++)
#pragma unroll
        for (int nt = 0; nt < 2; nt++)
          acc[mt][nt] = __builtin_amdgcn_mfma_f32_16x16x32_bf16(af[mt][kkk], bfr[nt], acc[mt][nt], 0, 0, 0);
    }
    __syncthreads();   // all waves done reading Bl

    // stage next jb's B (gl_lds, overlaps epilogue stores)
    if (jb < 5) {
#pragma unroll
      for (int i = 0; i < 8; i++) {
        int cid = wave * 8 + i;
        const unsigned short* src = Wb + ((size_t)((jb + 1) * 4096 + cid * 64 + lane)) * 8;
        __builtin_amdgcn_global_load_lds((const AS1 unsigned int*)src,
                                         (AS3 unsigned int*)(Bl + (size_t)cid * 512),
                                         16, 0, 0);
      }
    }

    // ---- epilogue: direct bf16 stores (wave's nt-pair covers 64B lines) ----
#pragma unroll
    for (int mt = 0; mt < 4; mt++)
#pragma unroll
      for (int nt = 0; nt < 2; nt++) {
        float bb = nt ? bb1 : bb0;
#pragma unroll
        for (int r = 0; r < 4; r++) {
          int row = s0 + wm * 64 + mt * 16 + quad * 4 + r;
          size_t go = ((size_t)b * SSL + row) * G3 + jb * 128 + wn * 32 + nt * 16 + n16;
          gi[go] = f2bf(acc[mt][nt][r] + bb);
        }
      }

    if (jb < 5) __syncthreads();   // drains vmcnt(0): next Bl ready
  }
}

// ---------------------------------------------------------------------------
// Kernel 2: persistent GRU scan — R7 version EXACT (known 610-618us).
// 64 blocks x 4 rows, 256 thr, 1 wave/SIMD; in-register gates via the
// replica-lane trick; one LDS roundtrip + one barrier per step.
// Bound (R9 insight): 96 MFMA/wave x 19.4 cy/SIMD = 1862 cy/step MFMA-pipe,
// 4x inflated by batch-column replication; fix = j-split across blocks w/
// device-scope h-exchange (next round).
// ---------------------------------------------------------------------------
__global__ __launch_bounds__(256, 1) void gru_scan(
    const float* __restrict__ tree, const int* __restrict__ mask,
    const unsigned short* __restrict__ wfrag, const float* __restrict__ bhh,
    const unsigned short* __restrict__ gi, float* __restrict__ out)
{
  // slot(kt,b,q) = kt*17 + b*4 + q (16B units); 17-pad spreads banks
  __shared__ __align__(16) unsigned short hbuf[2][1088];
  __shared__ int lsum[4];

  const int tid  = threadIdx.x;
  const int lane = tid & 63;
  const int w    = tid >> 6;
  const int n16  = lane & 15;
  const int quad = lane >> 4;
  const int b    = n16 & 3;          // batch row owned by this lane
  const int rep  = n16 >> 2;         // replica index -> owns mt tile = rep
  const int brow0 = blockIdx.x * 4;
  const int jbase = w * 64 + rep * 16 + quad * 4;  // 4 owned j's

  if (tid < 4) lsum[tid] = 0;

  // initial h (lane-resident, f32)
  f32x4 h4 = *(const f32x4*)(tree + (size_t)(brow0 + b) * HH + jbase);

  // h write slot: kt=jbase>>5, q=(jbase>>3)&3, half=(quad&1)*4
  const int wslot = ((w * 2 + (rep >> 1)) * 17 + b * 4 + ((rep & 1) * 2 + (quad >> 1))) * 8
                  + (quad & 1) * 4;
  {
    unsigned long long u =
        (unsigned long long)((unsigned)f2bf(h4[0]) | ((unsigned)f2bf(h4[1]) << 16)) |
        ((unsigned long long)((unsigned)f2bf(h4[2]) | ((unsigned)f2bf(h4[3]) << 16)) << 32);
    *(unsigned long long*)&hbuf[0][wslot] = u;
  }
  {
    const int* mp = mask + (size_t)(brow0 + w) * SSL + lane * 8;
    int4 a = *(const int4*)mp;
    int4 c = *(const int4*)(mp + 4);
    atomicAdd(&lsum[w], a.x + a.y + a.z + a.w + c.x + c.y + c.z + c.w);
  }

  // W fragments: g=0,1 -> AGPR (64 frags = 256 AGPR); g=2 -> VGPR (128 VGPR)
  short8 awA[2][4][8];
  short8 awV[4][8];
#pragma unroll
  for (int g = 0; g < 2; g++)
#pragma unroll
    for (int mt = 0; mt < 4; mt++)
#pragma unroll
      for (int kt = 0; kt < 8; kt++) {
        int F = ((w * 3 + g) * 4 + mt) * 8 + kt;
        awA[g][mt][kt] = *(const short8*)(wfrag + ((size_t)F * 64 + lane) * 8);
      }
#pragma unroll
  for (int mt = 0; mt < 4; mt++)
#pragma unroll
    for (int kt = 0; kt < 8; kt++) {
      int F = ((w * 3 + 2) * 4 + mt) * 8 + kt;
      awV[mt][kt] = *(const short8*)(wfrag + ((size_t)F * 64 + lane) * 8);
    }
  // Pin: opaque to remat; forces register class (R5 lesson).
#pragma unroll
  for (int g = 0; g < 2; g++)
#pragma unroll
    for (int mt = 0; mt < 4; mt++)
#pragma unroll
      for (int kt = 0; kt < 8; kt++)
        asm volatile("" : "+a"(awA[g][mt][kt]));
#pragma unroll
  for (int mt = 0; mt < 4; mt++)
#pragma unroll
    for (int kt = 0; kt < 8; kt++)
      asm volatile("" : "+v"(awV[mt][kt]));

  f32x4 bh4 = *(const f32x4*)(bhh + 2 * HH + jbase);

  // per-lane gi stream: batch row b, j's = jbase..jbase+3, 3 gates (8B each)
  const unsigned short* gip = gi + (size_t)(brow0 + b) * SSL * G3 + jbase;
  unsigned long long gA[3], gB[3];
#pragma unroll
  for (int g = 0; g < 3; g++) gA[g] = *(const unsigned long long*)(gip + (size_t)0 * G3 + g * HH);
#pragma unroll
  for (int g = 0; g < 3; g++) gB[g] = *(const unsigned long long*)(gip + (size_t)1 * G3 + g * HH);

  __syncthreads();
  int mylast = lsum[b] - 1; if (mylast < 0) mylast = 0;

  auto step = [&](int t, unsigned long long* gv) {
    const int cb = t & 1, nb = cb ^ 1;
    unsigned long long g0 = gv[0], g1 = gv[1], g2 = gv[2];

    // hb fragments first (starts LDS latency early)
    const unsigned short* hp = &hbuf[cb][0] + ((n16 & 3) * 4 + quad) * 8;
    short8 hb[8];
#pragma unroll
    for (int kt = 0; kt < 8; kt++)
      hb[kt] = *(const short8*)(hp + kt * (17 * 8));

    // prefetch gi for t+2 (covered by ~1 full step; no vmcnt drain at barrier)
    int tn = (t + 2 < SSL) ? t + 2 : SSL - 1;
    gv[0] = *(const unsigned long long*)(gip + (size_t)tn * G3 + 0 * HH);
    gv[1] = *(const unsigned long long*)(gip + (size_t)tn * G3 + 1 * HH);
    gv[2] = *(const unsigned long long*)(gip + (size_t)tn * G3 + 2 * HH);

    // ---- MFMA: 96 per wave, 6 independent chains per pass; select own tile ----
    f32x4 selR, selZ, selN;
#pragma unroll
    for (int mp = 0; mp < 2; mp++) {
      const int m0 = 2 * mp, m1 = 2 * mp + 1;
      f32x4 ar0 = f32x4{0.f, 0.f, 0.f, 0.f}, az0 = ar0, an0 = ar0;
      f32x4 ar1 = ar0, az1 = ar0, an1 = ar0;
#pragma unroll
      for (int kt = 0; kt < 8; kt++) {
        ar0 = __builtin_amdgcn_mfma_f32_16x16x32_bf16(awA[0][m0][kt], hb[kt], ar0, 0, 0, 0);
        ar1 = __builtin_amdgcn_mfma_f32_16x16x32_bf16(awA[0][m1][kt], hb[kt], ar1, 0, 0, 0);
        az0 = __builtin_amdgcn_mfma_f32_16x16x32_bf16(awA[1][m0][kt], hb[kt], az0, 0, 0, 0);
        az1 = __builtin_amdgcn_mfma_f32_16x16x32_bf16(awA[1][m1][kt], hb[kt], az1, 0, 0, 0);
        an0 = __builtin_amdgcn_mfma_f32_16x16x32_bf16(awV[m0][kt],    hb[kt], an0, 0, 0, 0);
        an1 = __builtin_amdgcn_mfma_f32_16x16x32_bf16(awV[m1][kt],    hb[kt], an1, 0, 0, 0);
      }
      if (mp == 0) {
        selR = (rep == 0) ? ar0 : ar1;   // rep 2,3 garbage, fixed next pass
        selZ = (rep == 0) ? az0 : az1;
        selN = (rep == 0) ? an0 : an1;
      } else {
        selR = (rep == 2) ? ar0 : ((rep == 3) ? ar1 : selR);
        selZ = (rep == 2) ? az0 : ((rep == 3) ? az1 : selZ);
        selN = (rep == 2) ? an0 : ((rep == 3) ? an1 : selN);
      }
    }

    // ---- gates in-register: 4 (j,b) elements per lane ----
#pragma unroll
    for (int e = 0; e < 4; e++) {
      float gr = bf2f((unsigned short)((g0 >> (16 * e)) & 0xFFFFull));
      float gz = bf2f((unsigned short)((g1 >> (16 * e)) & 0xFFFFull));
      float gn = bf2f((unsigned short)((g2 >> (16 * e)) & 0xFFFFull));
      float r = __builtin_amdgcn_rcpf(1.f + __expf(-(selR[e] + gr)));
      float z = __builtin_amdgcn_rcpf(1.f + __expf(-(selZ[e] + gz)));
      float a = gn + r * (selN[e] + bh4[e]);
      float nn = 1.f - 2.f * __builtin_amdgcn_rcpf(__expf(2.f * a) + 1.f);
      h4[e] = nn + z * (h4[e] - nn);
    }
    {
      unsigned long long u =
          (unsigned long long)((unsigned)f2bf(h4[0]) | ((unsigned)f2bf(h4[1]) << 16)) |
          ((unsigned long long)((unsigned)f2bf(h4[2]) | ((unsigned)f2bf(h4[3]) << 16)) << 32);
      *(unsigned long long*)&hbuf[nb][wslot] = u;
    }
    if (t == mylast) {   // per-lane predicate (last unmasked timestep of batch b)
      *(f32x4*)(out + (size_t)(brow0 + b) * HH + jbase) = h4;
    }
    sync_step();
  };

  for (int t = 0; t < SSL; t += 2) {
    step(t, gA);
    step(t + 1, gB);
  }
}

extern "C" void kernel_launch(void* const* d_in, const int* in_sizes, int n_in,
                              void* d_out, int out_size, void* d_ws, size_t ws_size,
                              hipStream_t stream) {
  const float* tree = (const float*)d_in[0];
  const float* seq  = (const float*)d_in[1];
  const int*   mask = (const int*)d_in[2];
  const float* Wih  = (const float*)d_in[3];
  const float* Whh  = (const float*)d_in[4];
  const float* bih  = (const float*)d_in[5];
  const float* bhh  = (const float*)d_in[6];
  float* out = (float*)d_out;

  unsigned short* gi      = (unsigned short*)d_ws;                       // 201,326,592 B
  unsigned short* wih_bf  = (unsigned short*)((char*)d_ws + 201326592);  // 393,216 B
  unsigned short* whh_frag= (unsigned short*)((char*)d_ws + 201719808);  // 393,216 B

  prep_pack<<<192, 256, 0, stream>>>(Wih, Whh, wih_bf, whh_frag);
  gi_gemm<<<1024, 512, 0, stream>>>(seq, wih_bf, bih, bhh, gi);
  gru_scan<<<64, 256, 0, stream>>>(tree, mask, whh_frag, bhh, gi, out);
}